// Round 1
// baseline (1440.293 us; speedup 1.0000x reference)
//
#include <hip/hip_runtime.h>

#define LEN_EPISODE 2048
#define NSTEPS (LEN_EPISODE - 1)
#define DT 0.01f

// One thread = one pendulum. Serial RK4 (3/8 rule) over 2047 steps.
// Latency-bound: 256 waves total, each wave effectively gets its own SIMD.
__global__ __launch_bounds__(64) void pend_kernel(
    const float* __restrict__ init,    // (B, 2)
    const float* __restrict__ params,  // (B, 4)
    float* __restrict__ out,           // (B, LEN_EPISODE)
    int B)
{
    int b = blockIdx.x * blockDim.x + threadIdx.x;
    if (b >= B) return;

    float th = init[2 * b + 0];
    float w  = init[2 * b + 1];

    const float4 p = *reinterpret_cast<const float4*>(params + 4 * b);
    const float omega = p.x, gamma = p.y, A = p.z, phi = p.w;

    const float w2   = omega * omega;          // omega^2
    const float Aw2  = A * omega * omega;      // A*omega^2 (matches ref order closely)
    const float c    = 6.28318530717958647692f * phi;  // 2*pi*phi
    const float dt   = DT;
    const float dt3  = (float)(0.01 / 3.0);    // dt/3
    const float dt23 = (float)(0.02 / 3.0);    // 2dt/3
    const float inv3 = 1.0f / 3.0f;

    float* __restrict__ orow = out + (size_t)b * LEN_EPISODE;

    // Buffer 4 outputs -> one float4 store (16B aligned: row start is 8KiB aligned).
    float4 buf;
    float* bufp = reinterpret_cast<float*>(&buf);
    bufp[0] = th;
    int bufn = 1;

    for (int i = 0; i < NSTEPS; ++i) {
        // ti as in jnp.linspace(0, dt*(N-1), N): i*dt computed in double, cast to f32
        const float tif = (float)((double)i * 0.01);

        // Force terms depend only on t (not on state) -> off the critical chain.
        const float f1 = Aw2 * cosf(c * tif);
        const float f2 = Aw2 * cosf(c * (tif + dt3));
        const float f3 = Aw2 * cosf(c * (tif + dt23));
        const float f4 = Aw2 * cosf(c * (tif + dt));

        // k1 = fun(ti, y)
        const float k1t = w;
        const float k1w = f1 - gamma * w - w2 * sinf(th);

        // k2 = fun(ti + dt/3, y + dt*k1/3)
        const float th2 = th + dt * k1t * inv3;
        const float w2s = w  + dt * k1w * inv3;
        const float k2t = w2s;
        const float k2w = f2 - gamma * w2s - w2 * sinf(th2);

        // k3 = fun(ti + 2dt/3, y + dt*(k2 - k1/3))
        const float th3 = th + dt * (k2t - k1t * inv3);
        const float w3s = w  + dt * (k2w - k1w * inv3);
        const float k3t = w3s;
        const float k3w = f3 - gamma * w3s - w2 * sinf(th3);

        // k4 = fun(ti + dt, y + dt*(k1 - k2 + k3))
        const float th4 = th + dt * (k1t - k2t + k3t);
        const float w4s = w  + dt * (k1w - k2w + k3w);
        const float k4t = w4s;
        const float k4w = f4 - gamma * w4s - w2 * sinf(th4);

        // y_next = y + dt*(k1 + 3*(k2+k3) + k4)*0.125
        th = th + dt * (k1t + 3.0f * (k2t + k3t) + k4t) * 0.125f;
        w  = w  + dt * (k1w + 3.0f * (k2w + k3w) + k4w) * 0.125f;

        bufp[bufn++] = th;
        if (bufn == 4) {
            *reinterpret_cast<float4*>(orow + (i + 1) - 3) = buf;
            bufn = 0;
        }
    }
}

extern "C" void kernel_launch(void* const* d_in, const int* in_sizes, int n_in,
                              void* d_out, int out_size, void* d_ws, size_t ws_size,
                              hipStream_t stream) {
    const float* init   = (const float*)d_in[0];
    const float* params = (const float*)d_in[1];
    float* out = (float*)d_out;
    const int B = in_sizes[0] / 2;  // 16384

    const int block = 64;                    // 1 wave per block -> spread over all CUs
    const int grid  = (B + block - 1) / block;  // 256 blocks
    pend_kernel<<<grid, block, 0, stream>>>(init, params, out, B);
}

// Round 4
// 656.006 us; speedup vs baseline: 2.1955x; 2.1955x over previous
//
#include <hip/hip_runtime.h>

#define LEN_EPISODE 2048
#define NSTEPS (LEN_EPISODE - 1)
#define DT 0.01f

// Fast sin/cos for |x| <= ~700 rad.
// Reduction: j = rint(x/pi); r = x - j*pi done in ONE f64 FMA (exact to 1e-16,
// then one f32 rounding: |err| <= 6e-8). Taylor poly on [-pi/2, pi/2].
// sign: sin(r + j*pi) = (-1)^j sin(r); cos likewise.
__device__ __forceinline__ float fsin(float x) {
    float j = __builtin_rintf(x * 0.318309886183790672f);   // x/pi
    float rf = (float)__builtin_fma((double)j, -3.14159265358979312, (double)x);
    float s = rf * rf;
    float p = -2.50521084e-8f;                // -1/11!
    p = __builtin_fmaf(p, s,  2.75573192e-6f);  //  1/9!
    p = __builtin_fmaf(p, s, -1.98412698e-4f);  // -1/7!
    p = __builtin_fmaf(p, s,  8.33333333e-3f);  //  1/5!
    p = __builtin_fmaf(p, s, -1.66666667e-1f);  // -1/3!
    float res = __builtin_fmaf(rf * s, p, rf);  // r + r*s*poly
    int ji = (int)j;
    return __int_as_float(__float_as_int(res) ^ (ji << 31));
}

__device__ __forceinline__ float fcos(float x) {
    float j = __builtin_rintf(x * 0.318309886183790672f);   // x/pi
    float rf = (float)__builtin_fma((double)j, -3.14159265358979312, (double)x);
    float s = rf * rf;
    float p =  2.08767570e-9f;                //  1/12!
    p = __builtin_fmaf(p, s, -2.75573192e-7f);  // -1/10!
    p = __builtin_fmaf(p, s,  2.48015873e-5f);  //  1/8!
    p = __builtin_fmaf(p, s, -1.38888889e-3f);  // -1/6!
    p = __builtin_fmaf(p, s,  4.16666667e-2f);  //  1/4!
    p = __builtin_fmaf(p, s, -0.5f);            // -1/2!
    float res = __builtin_fmaf(p, s, 1.0f);
    int ji = (int)j;
    return __int_as_float(__float_as_int(res) ^ (ji << 31));
}

// One thread = one pendulum. Serial RK4 (3/8 rule) over 2047 steps.
__global__ __launch_bounds__(64) void pend_kernel(
    const float* __restrict__ init,    // (B, 2)
    const float* __restrict__ params,  // (B, 4)
    float* __restrict__ out,           // (B, LEN_EPISODE)
    int B)
{
    int b = blockIdx.x * blockDim.x + threadIdx.x;
    if (b >= B) return;

    float th = init[2 * b + 0];
    float w  = init[2 * b + 1];

    const float4 p = *reinterpret_cast<const float4*>(params + 4 * b);
    const float omega = p.x, gamma = p.y, A = p.z, phi = p.w;

    const float w2   = omega * omega;          // omega^2
    const float Aw2  = A * omega * omega;      // A*omega^2
    const float c    = 6.28318530717958647692f * phi;  // 2*pi*phi
    const float dt   = DT;
    const float dt3  = (float)(0.01 / 3.0);    // dt/3
    const float dt23 = (float)(0.02 / 3.0);    // 2dt/3
    const float inv3 = 1.0f / 3.0f;

    float* __restrict__ orow = out + (size_t)b * LEN_EPISODE;

    float4 buf;
    float* bufp = reinterpret_cast<float*>(&buf);
    bufp[0] = th;
    int bufn = 1;

    for (int i = 0; i < NSTEPS; ++i) {
        const float tif = (float)((double)i * 0.01);

        // Force terms depend only on t -> off the state-dependent chain.
        const float f1 = Aw2 * fcos(c * tif);
        const float f2 = Aw2 * fcos(c * (tif + dt3));
        const float f3 = Aw2 * fcos(c * (tif + dt23));
        const float f4 = Aw2 * fcos(c * (tif + dt));

        // k1 = fun(ti, y)
        const float k1t = w;
        const float k1w = f1 - gamma * w - w2 * fsin(th);

        // k2 = fun(ti + dt/3, y + dt*k1/3)
        const float th2 = th + dt * k1t * inv3;
        const float w2s = w  + dt * k1w * inv3;
        const float k2t = w2s;
        const float k2w = f2 - gamma * w2s - w2 * fsin(th2);

        // k3 = fun(ti + 2dt/3, y + dt*(k2 - k1/3))
        const float th3 = th + dt * (k2t - k1t * inv3);
        const float w3s = w  + dt * (k2w - k1w * inv3);
        const float k3t = w3s;
        const float k3w = f3 - gamma * w3s - w2 * fsin(th3);

        // k4 = fun(ti + dt, y + dt*(k1 - k2 + k3))
        const float th4 = th + dt * (k1t - k2t + k3t);
        const float w4s = w  + dt * (k1w - k2w + k3w);
        const float k4t = w4s;
        const float k4w = f4 - gamma * w4s - w2 * fsin(th4);

        // y_next = y + dt*(k1 + 3*(k2+k3) + k4)*0.125
        th = th + dt * (k1t + 3.0f * (k2t + k3t) + k4t) * 0.125f;
        w  = w  + dt * (k1w + 3.0f * (k2w + k3w) + k4w) * 0.125f;

        bufp[bufn++] = th;
        if (bufn == 4) {
            *reinterpret_cast<float4*>(orow + (i + 1) - 3) = buf;
            bufn = 0;
        }
    }
}

extern "C" void kernel_launch(void* const* d_in, const int* in_sizes, int n_in,
                              void* d_out, int out_size, void* d_ws, size_t ws_size,
                              hipStream_t stream) {
    const float* init   = (const float*)d_in[0];
    const float* params = (const float*)d_in[1];
    float* out = (float*)d_out;
    const int B = in_sizes[0] / 2;  // 16384

    const int block = 64;                       // 1 wave per block -> spread over all CUs
    const int grid  = (B + block - 1) / block;  // 256 blocks
    pend_kernel<<<grid, block, 0, stream>>>(init, params, out, B);
}

// Round 5
// 366.601 us; speedup vs baseline: 3.9288x; 1.7894x over previous
//
#include <hip/hip_runtime.h>

#define LEN_EPISODE 2048
#define NSTEPS 2047

// ---- fast f32 sin, Cody-Waite reduction, valid |x| <~ 1e4 ----
// j = rint(x/pi); r = x - j*pi via 2-term split (pi_hi = 3.140625, 8 sig bits,
// j*pi_hi exact for |j| < 2^15). Taylor deg-11 on [-pi/2,pi/2]: abs err 5.7e-8.
__device__ __forceinline__ float fsin(float x) {
    float j = __builtin_rintf(x * 0.318309886183790672f);
    float r = __builtin_fmaf(j, -3.140625f, x);
    r = __builtin_fmaf(j, -9.67653589793238463e-4f, r);
    float s = r * r;
    float p = -2.50521084e-8f;                  // -1/11!
    p = __builtin_fmaf(p, s,  2.75573192e-6f);  //  1/9!
    p = __builtin_fmaf(p, s, -1.98412698e-4f);  // -1/7!
    p = __builtin_fmaf(p, s,  8.33333333e-3f);  //  1/5!
    p = __builtin_fmaf(p, s, -1.66666667e-1f);  // -1/3!
    float res = __builtin_fmaf(r * s, p, r);
    int ji = (int)j;
    return __int_as_float(__float_as_int(res) ^ (ji << 31));
}

// One RK4 (3/8-rule) step. Force terms come from a f64 rotor (rc,rs) tracking
// (cos,sin)(c*t): f1 = Aw2*rc; f2/f3 by f32 angle addition (+dt/3, +2dt/3);
// f4 = rotor advanced by dt (which becomes next step's f1 rotor).
#define STEP() do {                                                        \
    const float c0f = (float)rc, s0f = (float)rs;                          \
    const float f1 = Aw2 * c0f;                                            \
    const float f2 = __builtin_fmaf(-A2s, s0f, A2c * c0f);                 \
    const float f3 = __builtin_fmaf(-A3s, s0f, A3c * c0f);                 \
    const double rc_n = __builtin_fma(-rs, sd, rc * cd);                   \
    const double rs_n = __builtin_fma(rc, sd, rs * cd);                    \
    const float f4 = Aw2 * (float)rc_n;                                    \
    const float k1t = w;                                                   \
    const float k1w = f1 - gamma * w - w2 * fsin(th);                      \
    const float th2 = th + dt * k1t * inv3;                                \
    const float w2s = w  + dt * k1w * inv3;                                \
    const float k2t = w2s;                                                 \
    const float k2w = f2 - gamma * w2s - w2 * fsin(th2);                   \
    const float th3 = th + dt * (k2t - k1t * inv3);                        \
    const float w3s = w  + dt * (k2w - k1w * inv3);                        \
    const float k3t = w3s;                                                 \
    const float k3w = f3 - gamma * w3s - w2 * fsin(th3);                   \
    const float th4 = th + dt * (k1t - k2t + k3t);                         \
    const float w4s = w  + dt * (k1w - k2w + k3w);                         \
    const float k4t = w4s;                                                 \
    const float k4w = f4 - gamma * w4s - w2 * fsin(th4);                   \
    th = th + dt * (k1t + 3.0f * (k2t + k3t) + k4t) * 0.125f;              \
    w  = w  + dt * (k1w + 3.0f * (k2w + k3w) + k4w) * 0.125f;              \
    rc = rc_n; rs = rs_n;                                                  \
} while (0)

__global__ __launch_bounds__(64) void pend_kernel(
    const float* __restrict__ init,    // (B, 2)
    const float* __restrict__ params,  // (B, 4)
    float* __restrict__ out,           // (B, LEN_EPISODE)
    int B)
{
    int b = blockIdx.x * blockDim.x + threadIdx.x;
    if (b >= B) return;

    const float2 ic = *reinterpret_cast<const float2*>(init + 2 * b);
    float th = ic.x;
    float w  = ic.y;

    const float4 p = *reinterpret_cast<const float4*>(params + 4 * b);
    const float omega = p.x, gamma = p.y, A = p.z, phi = p.w;

    const float w2  = omega * omega;
    const float Aw2 = A * omega * omega;
    const float dt   = 0.01f;
    const float inv3 = 1.0f / 3.0f;

    // ---- rotor setup (once per thread, f64 libm) ----
    const double c_d = 6.283185307179586476925287 * (double)phi;  // 2*pi*phi
    const double cd = ::cos(c_d * 0.01);
    const double sd = ::sin(c_d * 0.01);
    double rc = 1.0, rs = 0.0;                     // cos/sin(c*t), t = 0
    const float cd3  = (float)::cos(c_d * (0.01 / 3.0));
    const float sd3  = (float)::sin(c_d * (0.01 / 3.0));
    const float cd23 = (float)::cos(c_d * (0.02 / 3.0));
    const float sd23 = (float)::sin(c_d * (0.02 / 3.0));
    const float A2c = Aw2 * cd3,  A2s = Aw2 * sd3;   // f2 = A2c*c - A2s*s
    const float A3c = Aw2 * cd23, A3s = Aw2 * sd23;  // f3 = A3c*c - A3s*s

    float* __restrict__ orow = out + (size_t)b * LEN_EPISODE;

    float va[8], vb[8];

    // ---- iteration 0 (peeled): slot 0 is the initial condition ----
    va[0] = th;
#pragma unroll
    for (int u = 1; u < 8; ++u) { STEP(); va[u] = th; }
    *reinterpret_cast<float4*>(orow + 0) = make_float4(va[0], va[1], va[2], va[3]);
    *reinterpret_cast<float4*>(orow + 4) = make_float4(va[4], va[5], va[6], va[7]);
#pragma unroll
    for (int u = 0; u < 8; ++u) { STEP(); vb[u] = th; }
    *reinterpret_cast<float4*>(orow + 8)  = make_float4(vb[0], vb[1], vb[2], vb[3]);
    *reinterpret_cast<float4*>(orow + 12) = make_float4(vb[4], vb[5], vb[6], vb[7]);

    // ---- iterations 1..127: 16 steps each; stores mid-loop so each buffer
    // has an 8-step (~1.5k cycle) gap before its registers are overwritten ----
    for (int k = 1; k < 128; ++k) {
        float* o = orow + (k << 4);
#pragma unroll
        for (int u = 0; u < 8; ++u) { STEP(); va[u] = th; }
        *reinterpret_cast<float4*>(o + 0) = make_float4(va[0], va[1], va[2], va[3]);
        *reinterpret_cast<float4*>(o + 4) = make_float4(va[4], va[5], va[6], va[7]);
#pragma unroll
        for (int u = 0; u < 8; ++u) { STEP(); vb[u] = th; }
        *reinterpret_cast<float4*>(o + 8)  = make_float4(vb[0], vb[1], vb[2], vb[3]);
        *reinterpret_cast<float4*>(o + 12) = make_float4(vb[4], vb[5], vb[6], vb[7]);
    }
}

extern "C" void kernel_launch(void* const* d_in, const int* in_sizes, int n_in,
                              void* d_out, int out_size, void* d_ws, size_t ws_size,
                              hipStream_t stream) {
    const float* init   = (const float*)d_in[0];
    const float* params = (const float*)d_in[1];
    float* out = (float*)d_out;
    const int B = in_sizes[0] / 2;  // 16384

    const int block = 64;                       // 1 wave per block -> 1 wave/CU
    const int grid  = (B + block - 1) / block;  // 256 blocks
    pend_kernel<<<grid, block, 0, stream>>>(init, params, out, B);
}

// Round 6
// 216.587 us; speedup vs baseline: 6.6499x; 1.6926x over previous
//
#include <hip/hip_runtime.h>

#define LEN_EPISODE 2048
#define NSTEPS 2047

// Stage sins via hardware v_sin_f32 (__sinf): ~3 instrs vs ~15 for the
// polynomial path. Input converted to revolutions; |th|<=~110 rad -> |rev|<=18,
// well inside the HW range. Absolute angle error ~6.6e-6 rad at |th|~100
// (f32 revolutions granularity) -- this round's accuracy experiment.

// One RK4 (3/8-rule) step. Force terms from f64 rotor (rc,rs) = (cos,sin)(c*t):
// f1 = Aw2*rc; f2/f3 by f32 angle addition; f4 = rotor advanced by dt.
#define STEP() do {                                                        \
    const float c0f = (float)rc, s0f = (float)rs;                          \
    const float f1 = Aw2 * c0f;                                            \
    const float f2 = __builtin_fmaf(-A2s, s0f, A2c * c0f);                 \
    const float f3 = __builtin_fmaf(-A3s, s0f, A3c * c0f);                 \
    const double rc_n = __builtin_fma(-rs, sd, rc * cd);                   \
    const double rs_n = __builtin_fma(rc, sd, rs * cd);                    \
    const float f4 = Aw2 * (float)rc_n;                                    \
    const float k1t = w;                                                   \
    const float k1w = f1 - gamma * w - w2 * __sinf(th);                    \
    const float th2 = th + dt * k1t * inv3;                                \
    const float w2s = w  + dt * k1w * inv3;                                \
    const float k2t = w2s;                                                 \
    const float k2w = f2 - gamma * w2s - w2 * __sinf(th2);                 \
    const float th3 = th + dt * (k2t - k1t * inv3);                        \
    const float w3s = w  + dt * (k2w - k1w * inv3);                        \
    const float k3t = w3s;                                                 \
    const float k3w = f3 - gamma * w3s - w2 * __sinf(th3);                 \
    const float th4 = th + dt * (k1t - k2t + k3t);                         \
    const float w4s = w  + dt * (k1w - k2w + k3w);                         \
    const float k4t = w4s;                                                 \
    const float k4w = f4 - gamma * w4s - w2 * __sinf(th4);                 \
    th = th + dt * (k1t + 3.0f * (k2t + k3t) + k4t) * 0.125f;              \
    w  = w  + dt * (k1w + 3.0f * (k2w + k3w) + k4w) * 0.125f;              \
    rc = rc_n; rs = rs_n;                                                  \
} while (0)

__global__ __launch_bounds__(64) void pend_kernel(
    const float* __restrict__ init,    // (B, 2)
    const float* __restrict__ params,  // (B, 4)
    float* __restrict__ out,           // (B, LEN_EPISODE)
    int B)
{
    int b = blockIdx.x * blockDim.x + threadIdx.x;
    if (b >= B) return;

    const float2 ic = *reinterpret_cast<const float2*>(init + 2 * b);
    float th = ic.x;
    float w  = ic.y;

    const float4 p = *reinterpret_cast<const float4*>(params + 4 * b);
    const float omega = p.x, gamma = p.y, A = p.z, phi = p.w;

    const float w2  = omega * omega;
    const float Aw2 = A * omega * omega;
    const float dt   = 0.01f;
    const float inv3 = 1.0f / 3.0f;

    // ---- rotor setup (once per thread, f64 libm) ----
    const double c_d = 6.283185307179586476925287 * (double)phi;  // 2*pi*phi
    const double cd = ::cos(c_d * 0.01);
    const double sd = ::sin(c_d * 0.01);
    double rc = 1.0, rs = 0.0;                     // cos/sin(c*t), t = 0
    const float cd3  = (float)::cos(c_d * (0.01 / 3.0));
    const float sd3  = (float)::sin(c_d * (0.01 / 3.0));
    const float cd23 = (float)::cos(c_d * (0.02 / 3.0));
    const float sd23 = (float)::sin(c_d * (0.02 / 3.0));
    const float A2c = Aw2 * cd3,  A2s = Aw2 * sd3;   // f2 = A2c*c - A2s*s
    const float A3c = Aw2 * cd23, A3s = Aw2 * sd23;  // f3 = A3c*c - A3s*s

    float* __restrict__ orow = out + (size_t)b * LEN_EPISODE;

    float va[8], vb[8];

    // ---- iteration 0 (peeled): slot 0 is the initial condition ----
    va[0] = th;
#pragma unroll
    for (int u = 1; u < 8; ++u) { STEP(); va[u] = th; }
    *reinterpret_cast<float4*>(orow + 0) = make_float4(va[0], va[1], va[2], va[3]);
    *reinterpret_cast<float4*>(orow + 4) = make_float4(va[4], va[5], va[6], va[7]);
#pragma unroll
    for (int u = 0; u < 8; ++u) { STEP(); vb[u] = th; }
    *reinterpret_cast<float4*>(orow + 8)  = make_float4(vb[0], vb[1], vb[2], vb[3]);
    *reinterpret_cast<float4*>(orow + 12) = make_float4(vb[4], vb[5], vb[6], vb[7]);

    // ---- iterations 1..127: 16 steps each; stores mid-loop so each buffer
    // has an 8-step gap before its registers are overwritten ----
    for (int k = 1; k < 128; ++k) {
        float* o = orow + (k << 4);
#pragma unroll
        for (int u = 0; u < 8; ++u) { STEP(); va[u] = th; }
        *reinterpret_cast<float4*>(o + 0) = make_float4(va[0], va[1], va[2], va[3]);
        *reinterpret_cast<float4*>(o + 4) = make_float4(va[4], va[5], va[6], va[7]);
#pragma unroll
        for (int u = 0; u < 8; ++u) { STEP(); vb[u] = th; }
        *reinterpret_cast<float4*>(o + 8)  = make_float4(vb[0], vb[1], vb[2], vb[3]);
        *reinterpret_cast<float4*>(o + 12) = make_float4(vb[4], vb[5], vb[6], vb[7]);
    }
}

extern "C" void kernel_launch(void* const* d_in, const int* in_sizes, int n_in,
                              void* d_out, int out_size, void* d_ws, size_t ws_size,
                              hipStream_t stream) {
    const float* init   = (const float*)d_in[0];
    const float* params = (const float*)d_in[1];
    float* out = (float*)d_out;
    const int B = in_sizes[0] / 2;  // 16384

    const int block = 64;                       // 1 wave per block -> 1 wave/CU
    const int grid  = (B + block - 1) / block;  // 256 blocks
    pend_kernel<<<grid, block, 0, stream>>>(init, params, out, B);
}

// Round 7
// 178.822 us; speedup vs baseline: 8.0543x; 1.2112x over previous
//
#include <hip/hip_runtime.h>

#define LEN_EPISODE 2048

// State kept in REVOLUTION units: U = theta/(2pi), V = w/(2pi).
// Then sin(theta) = v_sin_f32(U) directly (raw HW sin, input in revolutions) --
// the exact numeric path __sinf used in R6 (validated, absmax 0.25), minus the
// per-call multiply. All ODE scale factors absorbed into per-thread constants.
//
// Force cos(c*t) from an f32 rotor advanced by dt each step, re-based every 16
// steps from an f64 base rotor (drift <= 16 steps * 1e-7 ~ 2e-6, below the
// validated sin-arg granularity error 1.2e-5).

#define STEP() do {                                                        \
    const float f1 = fc;                                                   \
    const float f2 = __builtin_fmaf(nA2s, rsf, A2c * rcf);                 \
    const float f3 = __builtin_fmaf(nA3s, rsf, A3c * rcf);                 \
    const float rcn = __builtin_fmaf(nsdf, rsf, rcf * cdf);                \
    const float rsn = __builtin_fmaf(sdf, rcf, rsf * cdf);                 \
    const float fcn = Atil * rcn;                                          \
    const float f4 = fcn;                                                  \
    const float s1 = __builtin_amdgcn_sinf(U);                             \
    const float k1w = __builtin_fmaf(nw2t, s1, __builtin_fmaf(ngam, V, f1)); \
    const float U2 = __builtin_fmaf(c13, V, U);                            \
    const float V2 = __builtin_fmaf(c13, k1w, V);                          \
    const float s2 = __builtin_amdgcn_sinf(U2);                            \
    const float k2w = __builtin_fmaf(nw2t, s2, __builtin_fmaf(ngam, V2, f2)); \
    const float U3 = __builtin_fmaf(dt, V2, __builtin_fmaf(nc13, V, U));   \
    const float V3 = __builtin_fmaf(dt, k2w, __builtin_fmaf(nc13, k1w, V)); \
    const float s3 = __builtin_amdgcn_sinf(U3);                            \
    const float k3w = __builtin_fmaf(nw2t, s3, __builtin_fmaf(ngam, V3, f3)); \
    const float U4 = __builtin_fmaf(dt, (V - V2) + V3, U);                 \
    const float V4 = __builtin_fmaf(dt, (k1w - k2w) + k3w, V);             \
    const float s4 = __builtin_amdgcn_sinf(U4);                            \
    const float k4w = __builtin_fmaf(nw2t, s4, __builtin_fmaf(ngam, V4, f4)); \
    U = __builtin_fmaf(dt8, __builtin_fmaf(3.0f, V2 + V3, V) + V4, U);     \
    V = __builtin_fmaf(dt8, __builtin_fmaf(3.0f, k2w + k3w, k1w) + k4w, V); \
    rcf = rcn; rsf = rsn; fc = fcn;                                        \
} while (0)

__global__ __launch_bounds__(64) void pend_kernel(
    const float* __restrict__ init,    // (B, 2)
    const float* __restrict__ params,  // (B, 4)
    float* __restrict__ out,           // (B, LEN_EPISODE)
    int B)
{
    int b = blockIdx.x * blockDim.x + threadIdx.x;
    if (b >= B) return;

    const float2 ic = *reinterpret_cast<const float2*>(init + 2 * b);
    const float4 p  = *reinterpret_cast<const float4*>(params + 4 * b);
    const float omega = p.x, gamma = p.y, A = p.z, phi = p.w;

    const float twopi  = 6.283185307179586f;
    const float inv2pi = 0.15915494309189535f;

    float U = ic.x * inv2pi;            // theta in revolutions
    float V = ic.y * inv2pi;            // w in rev/s

    const float dt   = 0.01f;
    const float c13  = dt * (1.0f / 3.0f);
    const float nc13 = -c13;
    const float dt8  = dt * 0.125f;
    const float ngam = -gamma;
    const float nw2t = -(omega * omega) * inv2pi;  // -(w^2)/2pi
    const float Atil = A * omega * omega * inv2pi; // A*w^2/2pi

    // ---- rotor constants (f64 libm, once per thread) ----
    const double c_d = 6.283185307179586476925287 * (double)phi;  // 2*pi*phi
    const float cdf  = (float)::cos(c_d * 0.01);
    const float sdf  = (float)::sin(c_d * 0.01);
    const float nsdf = -sdf;
    const float A2c  = Atil * (float)::cos(c_d * (0.01 / 3.0));
    const float nA2s = -Atil * (float)::sin(c_d * (0.01 / 3.0));
    const float A3c  = Atil * (float)::cos(c_d * (0.02 / 3.0));
    const float nA3s = -Atil * (float)::sin(c_d * (0.02 / 3.0));
    // f64 base rotor at t = 15*dt (start of block k=1), advanced 16 steps/block
    const double cd16 = ::cos(c_d * 0.16);
    const double sd16 = ::sin(c_d * 0.16);
    double Bc = ::cos(c_d * 0.15);
    double Bs = ::sin(c_d * 0.15);

    float rcf = 1.0f, rsf = 0.0f;       // f32 rotor: cos/sin(c*t), t=0
    float fc  = Atil;                   // carried f1 = Atil*cos(c*t)

    float* __restrict__ orow = out + (size_t)b * LEN_EPISODE;
    float va[8], vb[8];

    // ---- iteration 0 (peeled, 15 steps): slot 0 = initial condition ----
    va[0] = ic.x;
#pragma unroll
    for (int u = 1; u < 8; ++u) { STEP(); va[u] = twopi * U; }
    *reinterpret_cast<float4*>(orow + 0) = make_float4(va[0], va[1], va[2], va[3]);
    *reinterpret_cast<float4*>(orow + 4) = make_float4(va[4], va[5], va[6], va[7]);
#pragma unroll
    for (int u = 0; u < 8; ++u) { STEP(); vb[u] = twopi * U; }
    *reinterpret_cast<float4*>(orow + 8)  = make_float4(vb[0], vb[1], vb[2], vb[3]);
    *reinterpret_cast<float4*>(orow + 12) = make_float4(vb[4], vb[5], vb[6], vb[7]);

    // ---- blocks k=1..127: 16 steps each; f32 rotor re-based from f64 ----
    for (int k = 1; k < 128; ++k) {
        rcf = (float)Bc; rsf = (float)Bs; fc = Atil * rcf;
        const double Bc_n = __builtin_fma(-Bs, sd16, Bc * cd16);
        const double Bs_n = __builtin_fma(Bc, sd16, Bs * cd16);
        Bc = Bc_n; Bs = Bs_n;
        float* o = orow + (k << 4);
#pragma unroll
        for (int u = 0; u < 8; ++u) { STEP(); va[u] = twopi * U; }
        *reinterpret_cast<float4*>(o + 0) = make_float4(va[0], va[1], va[2], va[3]);
        *reinterpret_cast<float4*>(o + 4) = make_float4(va[4], va[5], va[6], va[7]);
#pragma unroll
        for (int u = 0; u < 8; ++u) { STEP(); vb[u] = twopi * U; }
        *reinterpret_cast<float4*>(o + 8)  = make_float4(vb[0], vb[1], vb[2], vb[3]);
        *reinterpret_cast<float4*>(o + 12) = make_float4(vb[4], vb[5], vb[6], vb[7]);
    }
}

extern "C" void kernel_launch(void* const* d_in, const int* in_sizes, int n_in,
                              void* d_out, int out_size, void* d_ws, size_t ws_size,
                              hipStream_t stream) {
    const float* init   = (const float*)d_in[0];
    const float* params = (const float*)d_in[1];
    float* out = (float*)d_out;
    const int B = in_sizes[0] / 2;  // 16384

    const int block = 64;                       // 1 wave per block -> 1 wave/CU
    const int grid  = (B + block - 1) / block;  // 256 blocks
    pend_kernel<<<grid, block, 0, stream>>>(init, params, out, B);
}